// Round 13
// baseline (90.829 us; speedup 1.0000x reference)
//
#include <hip/hip_runtime.h>
#include <math.h>

#define T1 17
#define NN 2048
#define DIN 9
#define CC 8
#define KK 5
#define QB 4                   // queries per block (one per wave)
#define NT 20                  // donor tiles of 64 -> cap 1280 (proven cap)
#define NDCAP (NT * 64)
#define NQCAP 1280
#define PLANEF (NN * CC)       // 16384 floats per t-plane of xd
#define XD_BYTES (T1 * NN * CC * 4)

// ---------------------------------------------------------------------------
__global__ __launch_bounds__(128) void prep_a(
    const float* __restrict__ x_all, const int* __restrict__ mask,
    unsigned* __restrict__ pm, unsigned long long* __restrict__ wsbal,
    float* __restrict__ wscol, float* __restrict__ out) {
  const int row = blockIdx.x * 128 + threadIdx.x;
  const int lane = threadIdx.x & 63;
  const int g = row >> 6;
  unsigned m = 0;
#pragma unroll
  for (int t = 0; t < T1; ++t)
    m |= (mask[t * NN + row] == 0 ? 1u : 0u) << t;
  pm[row] = m;
  const bool v = (m >> 16) & 1u;
  const unsigned long long bal = __ballot(v);

  float s[CC];
#pragma unroll
  for (int c = 0; c < CC; ++c) s[c] = 0.f;
  if (v) {
    const float* r = x_all + ((size_t)16 * NN + row) * DIN;
#pragma unroll
    for (int c = 0; c < CC; ++c) {
      const float vv = r[c];
      s[c] = vv;
      out[row * CC + c] = vv;
    }
  }
#pragma unroll
  for (int off = 32; off > 0; off >>= 1) {
#pragma unroll
    for (int c = 0; c < CC; ++c) s[c] += __shfl_down(s[c], off);
  }
  if (lane == 0) {
    wsbal[g] = bal;
#pragma unroll
    for (int c = 0; c < CC; ++c) wscol[g * CC + c] = s[c];
  }
}

// ---------------------------------------------------------------------------
__global__ __launch_bounds__(1024) void prep_b(
    const unsigned* __restrict__ pm, const unsigned long long* __restrict__ wsbal,
    const float* __restrict__ wscol, int* __restrict__ dlist,
    unsigned* __restrict__ pmd, int* __restrict__ qlist,
    float* __restrict__ colmean, int* __restrict__ cnts) {
  __shared__ int dpre[33], qpre[33];
  __shared__ unsigned long long sbal[32];
  const int tid = threadIdx.x;
  if (tid < 32) sbal[tid] = wsbal[tid];
  __syncthreads();
  if (tid == 0) {
    int a = 0, b = 0;
    for (int g = 0; g < 32; ++g) {
      dpre[g] = a;
      qpre[g] = b;
      const int p = (int)__popcll(sbal[g]);
      a += p;
      b += 64 - p;
    }
    dpre[32] = a;
    qpre[32] = b;
    cnts[0] = a;  // ndon
    cnts[1] = b;  // nq
  }
  __syncthreads();
#pragma unroll
  for (int h = 0; h < 2; ++h) {
    const int row = tid + h * 1024;
    const unsigned m = pm[row];
    const int g = row >> 6, l = row & 63;
    const unsigned long long bal = sbal[g];
    const unsigned long long ltm = (1ull << l) - 1ull;
    if ((m >> 16) & 1u) {
      const int p = dpre[g] + (int)__popcll(bal & ltm);
      dlist[p] = row;
      pmd[p] = m;
    } else {
      const int p = qpre[g] + (int)__popcll((~bal) & ltm);
      qlist[p] = row;
    }
  }
  if (tid < CC) {
    float tot = 0.f;
#pragma unroll
    for (int g = 0; g < 32; ++g) tot += wscol[g * CC + tid];
    colmean[tid] = tot / fmaxf((float)dpre[32], 1.f);
  }
}

// ---------------------------------------------------------------------------
// Pack donor data t-major: xd[t][dn][c] = x_all[t][dlist[dn]][c]
__global__ void transpose_kernel(const float* __restrict__ x_all,
                                 const int* __restrict__ dlist,
                                 const int* __restrict__ cnts,
                                 float* __restrict__ xd) {
  const int u = blockIdx.x * 256 + threadIdx.x;
  if (u >= T1 * NN * CC) return;
  const int t = u / (NN * CC);
  const int rem = u % (NN * CC);
  const int dn = rem >> 3;
  const int c = rem & 7;
  if (dn < cnts[0]) xd[u] = x_all[((size_t)t * NN + dlist[dn]) * DIN + c];
}

// ---------------------------------------------------------------------------
// Main: block (256 thr = 4 waves) per 4 QUERIES; wave = query. Donor tiles
// (64 donors x 16t x 8ch = 32KB) double-buffered in LDS, async-staged
// (loads issued before compute, ds_write after). XOR swizzle ^((d&4)<<2) on
// global SOURCE offset + read offset -> conflict-free b128 reads. Distances
// in d0..d7[20] (static idx, tiles macro-expanded). Selection = R11-proven
// per-channel 5-round extraction (tie-exact, lowest-index == numpy top_k).
__global__ __launch_bounds__(256, 2) void knn_main(
    const float* __restrict__ x_all, const float* __restrict__ xd,
    const unsigned* __restrict__ pm, const unsigned* __restrict__ pmd,
    const int* __restrict__ qlist, const int* __restrict__ cnts,
    const float* __restrict__ colmean, float* __restrict__ out) {
  __shared__ float tb[2][16 * 64 * CC];  // 64KB double-buffered donor tile
  __shared__ float qlds[QB][16][CC];
  __shared__ float rcp17[32];
  const int nq = cnts[1];
  const int bid = blockIdx.x;
  if (bid * QB >= nq) return;
  const int ndon = cnts[0];
  const int tid = threadIdx.x;
  const int lane = tid & 63;
  const int w = tid >> 6;       // wave = query slot
  const int qidx = bid * QB + w;
  const bool qok = qidx < nq;
  const int i = qlist[qok ? qidx : bid * QB];
  const unsigned mi = (unsigned)__builtin_amdgcn_readfirstlane((int)pm[i]);

  if (tid < 32) rcp17[tid] = 17.f / (float)tid;  // [0]=inf, guarded by ok
#pragma unroll
  for (int h = tid; h < QB * 16 * CC; h += 256) {
    const int q = h >> 7, t = (h >> 3) & 15, c = h & 7;
    const int qq = bid * QB + q;
    const int iq = (qq < nq) ? qlist[qq] : qlist[bid * QB];
    qlds[q][t][c] = x_all[((size_t)t * NN + iq) * DIN + c];
  }

  // staging geometry: per tile, 8 rounds of (256 thr x 16B) = two t-planes
  const int thalf = tid >> 7;                    // which t-plane of the pair
  const int ip = tid & 127;                      // 16B slot within plane pair
  const int ssw = (ip * 4) ^ ((tid & 8) >> 1);   // source float off (pre-swizzled)
  const int lp = ip * 4;                         // linear LDS float off
  const int swr = lane & 4;                      // read-side swizzle (floats)

  float d0[NT], d1[NT], d2[NT], d3[NT], d4[NT], d5[NT], d6[NT], d7[NT];
#pragma unroll
  for (int u = 0; u < NT; ++u) {
    d0[u] = INFINITY; d1[u] = INFINITY; d2[u] = INFINITY; d3[u] = INFINITY;
    d4[u] = INFINITY; d5[u] = INFINITY; d6[u] = INFINITY; d7[u] = INFINITY;
  }

  float4 sv0, sv1, sv2, sv3, sv4, sv5, sv6, sv7;

#define STAGE_LOAD(U)                                                        \
  {                                                                          \
    const float* sb = xd + (size_t)(U) * 512 + ssw;                          \
    sv0 = *(const float4*)(sb + (size_t)(0 + thalf) * PLANEF);               \
    sv1 = *(const float4*)(sb + (size_t)(2 + thalf) * PLANEF);               \
    sv2 = *(const float4*)(sb + (size_t)(4 + thalf) * PLANEF);               \
    sv3 = *(const float4*)(sb + (size_t)(6 + thalf) * PLANEF);               \
    sv4 = *(const float4*)(sb + (size_t)(8 + thalf) * PLANEF);               \
    sv5 = *(const float4*)(sb + (size_t)(10 + thalf) * PLANEF);              \
    sv6 = *(const float4*)(sb + (size_t)(12 + thalf) * PLANEF);              \
    sv7 = *(const float4*)(sb + (size_t)(14 + thalf) * PLANEF);              \
  }

#define STAGE_WRITE(BUF)                                                     \
  {                                                                          \
    float* wb = &tb[BUF][thalf * 512 + lp];                                  \
    *(float4*)(wb + 0 * 1024) = sv0;                                         \
    *(float4*)(wb + 1 * 1024) = sv1;                                         \
    *(float4*)(wb + 2 * 1024) = sv2;                                         \
    *(float4*)(wb + 3 * 1024) = sv3;                                         \
    *(float4*)(wb + 4 * 1024) = sv4;                                         \
    *(float4*)(wb + 5 * 1024) = sv5;                                         \
    *(float4*)(wb + 6 * 1024) = sv6;                                         \
    *(float4*)(wb + 7 * 1024) = sv7;                                         \
  }

#define COMPUTE(U, BUF)                                                      \
  {                                                                          \
    const int dn = (U) * 64 + lane;                                          \
    const unsigned mk = (dn < ndon) ? (mi & pmd[dn]) : 0u;                   \
    float a0 = 0.f, a1 = 0.f, a2 = 0.f, a3 = 0.f;                            \
    float a4 = 0.f, a5 = 0.f, a6 = 0.f, a7 = 0.f;                            \
    unsigned tm = mi & 0xFFFFu;                                              \
    while (tm) {                                                             \
      const int t = __ffs(tm) - 1;                                           \
      tm &= tm - 1u;                                                         \
      const int em = ((int)(mk << (31 - t))) >> 31;                          \
      const float4 qv0 = *(const float4*)&qlds[w][t][0];                     \
      const float4 qv1 = *(const float4*)&qlds[w][t][4];                     \
      const float* db = &tb[BUF][t * 512 + lane * 8];                        \
      const float4 dv0 = *(const float4*)(db + swr);                         \
      const float4 dv1 = *(const float4*)(db + (4 ^ swr));                   \
      float e;                                                               \
      e = qv0.x - dv0.x; e = __int_as_float(__float_as_int(e) & em); a0 = fmaf(e, e, a0); \
      e = qv0.y - dv0.y; e = __int_as_float(__float_as_int(e) & em); a1 = fmaf(e, e, a1); \
      e = qv0.z - dv0.z; e = __int_as_float(__float_as_int(e) & em); a2 = fmaf(e, e, a2); \
      e = qv0.w - dv0.w; e = __int_as_float(__float_as_int(e) & em); a3 = fmaf(e, e, a3); \
      e = qv1.x - dv1.x; e = __int_as_float(__float_as_int(e) & em); a4 = fmaf(e, e, a4); \
      e = qv1.y - dv1.y; e = __int_as_float(__float_as_int(e) & em); a5 = fmaf(e, e, a5); \
      e = qv1.z - dv1.z; e = __int_as_float(__float_as_int(e) & em); a6 = fmaf(e, e, a6); \
      e = qv1.w - dv1.w; e = __int_as_float(__float_as_int(e) & em); a7 = fmaf(e, e, a7); \
    }                                                                        \
    const int cnt = __popc(mk);                                              \
    const float sc = rcp17[cnt & 31];                                        \
    const bool ok = cnt > 0;                                                 \
    d0[U] = ok ? sqrtf(a0 * sc) : INFINITY;                                  \
    d1[U] = ok ? sqrtf(a1 * sc) : INFINITY;                                  \
    d2[U] = ok ? sqrtf(a2 * sc) : INFINITY;                                  \
    d3[U] = ok ? sqrtf(a3 * sc) : INFINITY;                                  \
    d4[U] = ok ? sqrtf(a4 * sc) : INFINITY;                                  \
    d5[U] = ok ? sqrtf(a5 * sc) : INFINITY;                                  \
    d6[U] = ok ? sqrtf(a6 * sc) : INFINITY;                                  \
    d7[U] = ok ? sqrtf(a7 * sc) : INFINITY;                                  \
  }

#define TILE(U)                                                              \
  if ((U) * 64 < ndon) {                                                     \
    if (((U) + 1) < NT && ((U) + 1) * 64 < ndon) STAGE_LOAD((U) + 1);        \
    COMPUTE(U, (U) & 1);                                                     \
    if (((U) + 1) < NT && ((U) + 1) * 64 < ndon) {                           \
      STAGE_WRITE(((U) + 1) & 1);                                            \
      __syncthreads();                                                       \
    }                                                                        \
  }

  STAGE_LOAD(0);
  STAGE_WRITE(0);
  __syncthreads();  // also covers qlds/rcp17

  TILE(0); TILE(1); TILE(2); TILE(3); TILE(4);
  TILE(5); TILE(6); TILE(7); TILE(8); TILE(9);
  TILE(10); TILE(11); TILE(12); TILE(13); TILE(14);
  TILE(15); TILE(16); TILE(17); TILE(18); TILE(19);

  // ---- selection per channel (R11-proven): ascending (d, j) extraction ----
  const float* __restrict__ xd16 = xd + (size_t)16 * PLANEF;

#define SELECT_CH(DC, CIDX)                                                  \
  {                                                                          \
    float sum = 0.f;                                                         \
    int cn = 0;                                                              \
    for (int k = 0; k < KK; ++k) {                                           \
      float g = DC[0];                                                       \
      _Pragma("unroll")                                                      \
      for (int u = 1; u < NT; ++u) g = fminf(g, DC[u]);                      \
      _Pragma("unroll")                                                      \
      for (int off = 32; off > 0; off >>= 1) g = fminf(g, __shfl_xor(g, off)); \
      if (!(g < INFINITY)) break;                                            \
      int jloc = 0x7FFFFFFF;                                                 \
      _Pragma("unroll")                                                      \
      for (int u = NT - 1; u >= 0; --u)                                      \
        if (DC[u] == g) jloc = u * 64 + lane;                                \
      _Pragma("unroll")                                                      \
      for (int off = 32; off > 0; off >>= 1) jloc = min(jloc, __shfl_xor(jloc, off)); \
      const int jgs = __builtin_amdgcn_readfirstlane(jloc);                  \
      const int tu = jgs >> 6, tl = jgs & 63;                                \
      _Pragma("unroll")                                                      \
      for (int u = 0; u < NT; ++u)                                           \
        if (u == tu) DC[u] = (lane == tl) ? INFINITY : DC[u];                \
      sum += xd16[jgs * CC + (CIDX)];                                        \
      ++cn;                                                                  \
    }                                                                        \
    if (qok && lane == 0)                                                    \
      out[i * CC + (CIDX)] = (cn > 0) ? sum / (float)cn : colmean[(CIDX)];   \
  }

  SELECT_CH(d0, 0);
  SELECT_CH(d1, 1);
  SELECT_CH(d2, 2);
  SELECT_CH(d3, 3);
  SELECT_CH(d4, 4);
  SELECT_CH(d5, 5);
  SELECT_CH(d6, 6);
  SELECT_CH(d7, 7);
}

// ---------------------------------------------------------------------------
extern "C" void kernel_launch(void* const* d_in, const int* in_sizes, int n_in,
                              void* d_out, int out_size, void* d_ws, size_t ws_size,
                              hipStream_t stream) {
  const float* x_all = (const float*)d_in[0];  // [17, 2048, 9] f32
  const int* mask = (const int*)d_in[1];       // [17, 2048] i32
  float* out = (float*)d_out;                  // [2048, 8] f32

  char* ws = (char*)d_ws;
  float* xd = (float*)ws;
  unsigned* pm = (unsigned*)(ws + XD_BYTES);
  int* dlist = (int*)(ws + XD_BYTES + NN * 4);
  unsigned* pmd = (unsigned*)(ws + XD_BYTES + NN * 8);
  int* qlist = (int*)(ws + XD_BYTES + NN * 12);
  float* colmean = (float*)(ws + XD_BYTES + NN * 16);
  int* cnts = (int*)(ws + XD_BYTES + NN * 16 + CC * 4);
  unsigned long long* wsbal = (unsigned long long*)(ws + XD_BYTES + NN * 16 + CC * 4 + 64);
  float* wscol = (float*)(ws + XD_BYTES + NN * 16 + CC * 4 + 64 + 32 * 8);

  prep_a<<<16, 128, 0, stream>>>(x_all, mask, pm, wsbal, wscol, out);
  prep_b<<<1, 1024, 0, stream>>>(pm, wsbal, wscol, dlist, pmd, qlist, colmean, cnts);
  transpose_kernel<<<(T1 * NN * CC + 255) / 256, 256, 0, stream>>>(x_all, dlist, cnts, xd);
  knn_main<<<NQCAP / QB, 256, 0, stream>>>(x_all, xd, pm, pmd, qlist, cnts, colmean, out);
}